// Round 4
// baseline (315.629 us; speedup 1.0000x reference)
//
#include <hip/hip_runtime.h>
#include <math.h>

typedef unsigned short ushort_t;
typedef __bf16 bf16x8 __attribute__((ext_vector_type(8)));
typedef ushort_t ushort8v __attribute__((ext_vector_type(8)));
typedef float f32x4 __attribute__((ext_vector_type(4)));

#define B_SZ   4
#define SEQ    8192
#define M_ROWS (B_SZ * SEQ)   // 32768
#define CH     128
#define NC     (SEQ / CH)     // 64

__device__ __forceinline__ ushort_t f2bf(float f) {
    unsigned u = __float_as_uint(f);
    u = u + 0x7fffu + ((u >> 16) & 1u);
    return (ushort_t)(u >> 16);
}
__device__ __forceinline__ float bf2f(ushort_t b) {
    return __uint_as_float(((unsigned)b) << 16);
}

__device__ __forceinline__ void load16_lds(const void* g, void* l) {
    __builtin_amdgcn_global_load_lds(
        (const __attribute__((address_space(1))) unsigned int*)g,
        (__attribute__((address_space(3))) unsigned int*)l, 16, 0, 0);
}

// ---------------------------------------------------------------------------
// prep: Bmat[k][h] (k = d*512+2p interleaved), Cmat[h][k], abar, apow=a^128,
// a32=a^32.
__global__ void prep_kernel(const float* __restrict__ Lre,
                            const float* __restrict__ Lim,
                            const float* __restrict__ ldt,
                            const float* __restrict__ Bre,
                            const float* __restrict__ Bim,
                            const float* __restrict__ Cre,
                            const float* __restrict__ Cim,
                            float* __restrict__ abar,
                            float* __restrict__ apow,
                            float* __restrict__ a32t,
                            ushort_t* __restrict__ Bmat,
                            ushort_t* __restrict__ Cmat) {
    int idx = blockIdx.x * 256 + threadIdx.x;   // 0 .. 262143
    int h = idx & 511;
    int p = (idx >> 9) & 255;
    int d = idx >> 17;
    int ip = d * 256 + p;
    float lr = Lre[ip], li = Lim[ip];
    float dt = expf(ldt[ip]);
    float e   = expf(lr * dt);
    float ang = li * dt;
    float ar = e * cosf(ang), ai = e * sinf(ang);
    float nr = ar - 1.0f, ni = ai;
    float den = lr * lr + li * li;
    float cr = (nr * lr + ni * li) / den;
    float ci = (ni * lr - nr * li) / den;
    float br = Bre[idx], bi = Bim[idx];
    Bmat[(d * 512 + 2 * p) * 512 + h]     = f2bf(cr * br - ci * bi);
    Bmat[(d * 512 + 2 * p + 1) * 512 + h] = f2bf(cr * bi + ci * br);
    if (h == 0) {
        int o = d * 512 + 2 * p;
        abar[o] = ar;  abar[o + 1] = ai;
        float eC = expf(lr * dt * 128.f);
        float aC = ang * 128.f;
        apow[o] = eC * cosf(aC);  apow[o + 1] = eC * sinf(aC);
        float e32 = expf(lr * dt * 32.f);
        float a32 = ang * 32.f;
        a32t[o] = e32 * cosf(a32);  a32t[o + 1] = e32 * sinf(a32);
    }
    int p2 = idx & 255;
    int h2 = (idx >> 8) & 511;
    int d2 = idx >> 17;
    Cmat[h2 * 1024 + d2 * 512 + 2 * p2]     = f2bf(Cre[idx]);
    Cmat[h2 * 1024 + d2 * 512 + 2 * p2 + 1] = f2bf(-Cim[idx]);
}

// pw[l][pg] = a_pg^(l+1) for dir0, a_pg^(128-l) for dir1 (complex, fp32).
__global__ void pw_kernel(const float* __restrict__ Lre,
                          const float* __restrict__ Lim,
                          const float* __restrict__ ldt,
                          float* __restrict__ pw) {
    int l  = blockIdx.x;      // 0..127
    int pg = threadIdx.x;     // 0..511
    int d = pg >> 8, p = pg & 255;
    int ip = d * 256 + p;
    float lr = Lre[ip], li = Lim[ip];
    float dt = expf(ldt[ip]);
    float ex = (d == 0) ? (float)(l + 1) : (float)(128 - l);
    float mag = expf(lr * dt * ex);
    float ang = li * dt * ex;
    pw[(l * 512 + pg) * 2]     = mag * cosf(ang);
    pw[(l * 512 + pg) * 2 + 1] = mag * sinf(ang);
}

// ---------------------------------------------------------------------------
// GEMM1 fused with chunk-local scan.
// A = fp32 x[M][512] (inline bf16 convert), B = Bmat[1024][512] bf16.
// Each block: m-tile == chunk mt (128 rows), n-tile nt (128 cols = 64 complex
// channels, direction-uniform). Computes bu tile, local-scans it, writes
// s_local (bf16) to SB[M][1024] and chunk carry.
__global__ __launch_bounds__(256)
void gemm1_scan(const float* __restrict__ Xf, const ushort_t* __restrict__ Bm,
                ushort_t* __restrict__ SB, const float* __restrict__ abar,
                const float* __restrict__ a32t, float* __restrict__ carry) {
    __shared__ __align__(16) char ldsraw[36864];
    ushort_t* As      = (ushort_t*)ldsraw;            // 8 KB (K-loop)
    ushort_t* Bs      = (ushort_t*)(ldsraw + 8192);   // 8 KB (K-loop)
    ushort_t* scanbuf = (ushort_t*)ldsraw;            // 32 KB (post-loop)
    float*    segE    = (float*)(ldsraw + 32768);     // 2 KB
    float*    cin     = (float*)(ldsraw + 34816);     // 2 KB

    const int tid  = threadIdx.x;
    const int lane = tid & 63;
    const int wv   = tid >> 6;
    const int wrow = wv >> 1, wcol = wv & 1;
    const int l15  = lane & 15, lq = lane >> 4;

    const int lin = blockIdx.x;
    const int xcd = lin & 7;
    const int j   = lin >> 3;
    const int mt  = xcd * 32 + (j >> 3);   // chunk id 0..255
    const int nt  = j & 7;
    const int m0 = mt * 128;
    const int n0 = nt * 128;

    f32x4 acc[4][4];
#pragma unroll
    for (int i = 0; i < 4; ++i)
#pragma unroll
        for (int jj = 0; jj < 4; ++jj)
            acc[i][jj] = (f32x4){0.f, 0.f, 0.f, 0.f};

    const int grow_l = lane >> 2;
    const int gk8    = (lane & 3) * 8;

    // A staging geometry: thread -> row (0..127), k-half (0 or 16)
    const int arow = tid >> 1;
    const int akh  = (tid & 1) << 4;
    const float* Ap = &Xf[(size_t)(m0 + arow) * 512 + akh];

    const ushort_t* aF = As + (wrow * 64 + l15) * 32 + lq * 8;
    const ushort_t* bF = Bs + (wcol * 64 + l15) * 32 + lq * 8;

    for (int kt = 0; kt < 512; kt += 32) {
        float4 a0 = *(const float4*)(Ap + kt);
        float4 a1 = *(const float4*)(Ap + kt + 4);
        float4 a2 = *(const float4*)(Ap + kt + 8);
        float4 a3 = *(const float4*)(Ap + kt + 12);
        __syncthreads();
#pragma unroll
        for (int j2 = 0; j2 < 2; ++j2) {
            const int r0 = j2 * 64 + wv * 16;
            load16_lds(&Bm[(size_t)(n0 + r0 + grow_l) * 512 + kt + gk8],
                       (void*)&Bs[r0 * 32]);
        }
        ushort8v w0, w1;
        w0[0] = f2bf(a0.x); w0[1] = f2bf(a0.y); w0[2] = f2bf(a0.z); w0[3] = f2bf(a0.w);
        w0[4] = f2bf(a1.x); w0[5] = f2bf(a1.y); w0[6] = f2bf(a1.z); w0[7] = f2bf(a1.w);
        w1[0] = f2bf(a2.x); w1[1] = f2bf(a2.y); w1[2] = f2bf(a2.z); w1[3] = f2bf(a2.w);
        w1[4] = f2bf(a3.x); w1[5] = f2bf(a3.y); w1[6] = f2bf(a3.z); w1[7] = f2bf(a3.w);
        *(ushort8v*)&As[arow * 32 + akh]     = w0;
        *(ushort8v*)&As[arow * 32 + akh + 8] = w1;
        __syncthreads();

        bf16x8 af[4], bfr[4];
#pragma unroll
        for (int mi = 0; mi < 4; ++mi) {
            union { ushort8v u; bf16x8 b; } cv;
            cv.u = *(const ushort8v*)(aF + mi * 512);
            af[mi] = cv.b;
        }
#pragma unroll
        for (int ni = 0; ni < 4; ++ni) {
            union { ushort8v u; bf16x8 b; } cv;
            cv.u = *(const ushort8v*)(bF + ni * 512);
            bfr[ni] = cv.b;
        }
#pragma unroll
        for (int mi = 0; mi < 4; ++mi)
#pragma unroll
            for (int ni = 0; ni < 4; ++ni)
                acc[mi][ni] = __builtin_amdgcn_mfma_f32_16x16x32_bf16(
                    af[mi], bfr[ni], acc[mi][ni], 0, 0, 0);
    }

    // ---- repack acc -> scanbuf bf16 [row][col] (overlaps As/Bs)
    __syncthreads();
#pragma unroll
    for (int mi = 0; mi < 4; ++mi)
#pragma unroll
        for (int ni = 0; ni < 4; ++ni) {
            const int col = wcol * 64 + ni * 16 + l15;
#pragma unroll
            for (int r = 0; r < 4; ++r) {
                const int row = wrow * 64 + mi * 16 + lq * 4 + r;
                scanbuf[row * 128 + col] = f2bf(acc[mi][ni][r]);
            }
        }
    __syncthreads();

    // ---- chunk-local scan: 64 complex channels x 4 segments of 32
    const int ch = tid & 63;
    const int sg = tid >> 6;
    const int pg = (n0 >> 1) + ch;          // global complex channel
    const bool bwd = (pg >= 256);           // uniform per block
    const float ar = abar[2 * pg], ai = abar[2 * pg + 1];

    float sr = 0.f, si = 0.f;
    for (int i = 0; i < 32; ++i) {
        int l = sg * 32 + i;
        int row = bwd ? (127 - l) : l;
        unsigned u = *(const unsigned*)&scanbuf[row * 128 + 2 * ch];
        float re = bf2f((ushort_t)(u & 0xffffu));
        float im = bf2f((ushort_t)(u >> 16));
        float nr = fmaf(ar, sr, fmaf(-ai, si, re));
        float ni2 = fmaf(ar, si, fmaf(ai, sr, im));
        sr = nr; si = ni2;
    }
    segE[(ch * 4 + sg) * 2]     = sr;
    segE[(ch * 4 + sg) * 2 + 1] = si;
    __syncthreads();

    if (sg == 0) {
        const float pr = a32t[2 * pg], pi = a32t[2 * pg + 1];
        float er = 0.f, ei = 0.f;
        for (int s2 = 0; s2 < 4; ++s2) {
            cin[(ch * 4 + s2) * 2]     = er;
            cin[(ch * 4 + s2) * 2 + 1] = ei;
            float cr = segE[(ch * 4 + s2) * 2];
            float ci = segE[(ch * 4 + s2) * 2 + 1];
            float nr = fmaf(pr, er, fmaf(-pi, ei, cr));
            float ni2 = fmaf(pr, ei, fmaf(pi, er, ci));
            er = nr; ei = ni2;
        }
        carry[mt * 1024 + 2 * pg]     = er;
        carry[mt * 1024 + 2 * pg + 1] = ei;
    }
    __syncthreads();

    sr = cin[(ch * 4 + sg) * 2];
    si = cin[(ch * 4 + sg) * 2 + 1];
    ushort_t* outp = SB + (size_t)m0 * 1024 + n0 + 2 * ch;
    for (int i = 0; i < 32; ++i) {
        int l = sg * 32 + i;
        int row = bwd ? (127 - l) : l;
        unsigned u = *(const unsigned*)&scanbuf[row * 128 + 2 * ch];
        float re = bf2f((ushort_t)(u & 0xffffu));
        float im = bf2f((ushort_t)(u >> 16));
        float nr = fmaf(ar, sr, fmaf(-ai, si, re));
        float ni2 = fmaf(ar, si, fmaf(ai, sr, im));
        sr = nr; si = ni2;
        *(unsigned*)(outp + (size_t)row * 1024) =
            ((unsigned)f2bf(si) << 16) | (unsigned)f2bf(sr);
    }
}

// ---------------------------------------------------------------------------
__global__ __launch_bounds__(512)
void scan_comb(const float* __restrict__ carry, float* __restrict__ init,
               const float* __restrict__ apow) {
    int b = blockIdx.x, t = threadIdx.x;
    int dir = t >> 8, p = t & 255;
    float pr = apow[dir * 512 + 2 * p], pi = apow[dir * 512 + 2 * p + 1];
    float sr = 0.f, si = 0.f;
    for (int cc = 0; cc < NC; ++cc) {
        int c = dir ? (NC - 1 - cc) : cc;
        int o = (b * NC + c) * 1024 + dir * 512 + 2 * p;
        init[o] = sr; init[o + 1] = si;
        float cr = carry[o], ci = carry[o + 1];
        float nr = fmaf(pr, sr, fmaf(-pi, si, cr));
        float ni = fmaf(pr, si, fmaf(pi, sr, ci));
        sr = nr; si = ni;
    }
}

// ---------------------------------------------------------------------------
// Elementwise fix-up: SB[m][k] += pw[lrow][k/2] * init[chunk][k/2]
__global__ __launch_bounds__(256)
void correct_kernel(ushort_t* __restrict__ SB, const float* __restrict__ pw,
                    const float* __restrict__ initb) {
    unsigned tid = blockIdx.x * 256 + threadIdx.x;  // 4,194,304 total
    int m  = tid >> 7;
    int k8 = (tid & 127) * 8;
    int lrow  = m & 127;
    int chunk = m >> 7;
    ushort_t* sp = SB + (size_t)m * 1024 + k8;
    uint4 sv = *(const uint4*)sp;
    unsigned uu[4] = {sv.x, sv.y, sv.z, sv.w};
    const float* pwp = pw + ((size_t)lrow * 512 + (k8 >> 1)) * 2;
    const float* inp = initb + (size_t)chunk * 1024 + k8;
    float4 pw0 = *(const float4*)pwp;
    float4 pw1 = *(const float4*)(pwp + 4);
    float4 in0 = *(const float4*)inp;
    float4 in1 = *(const float4*)(inp + 4);
    float pr[4] = {pw0.x, pw0.z, pw1.x, pw1.z};
    float pi[4] = {pw0.y, pw0.w, pw1.y, pw1.w};
    float ir[4] = {in0.x, in0.z, in1.x, in1.z};
    float ii[4] = {in0.y, in0.w, in1.y, in1.w};
#pragma unroll
    for (int q = 0; q < 4; ++q) {
        float sr = bf2f((ushort_t)(uu[q] & 0xffffu));
        float si = bf2f((ushort_t)(uu[q] >> 16));
        sr = fmaf(pr[q], ir[q], fmaf(-pi[q], ii[q], sr));
        si = fmaf(pr[q], ii[q], fmaf(pi[q], ir[q], si));
        uu[q] = ((unsigned)f2bf(si) << 16) | (unsigned)f2bf(sr);
    }
    uint4 ov = {uu[0], uu[1], uu[2], uu[3]};
    *(uint4*)sp = ov;
}

// ---------------------------------------------------------------------------
// GEMM2: y[M][512] = SB[M][1024] * Cmat[512][1024]^T + x*(D0+D1)
__global__ __launch_bounds__(256)
void gemm2_mfma(const ushort_t* __restrict__ A, const ushort_t* __restrict__ Bm,
                float* __restrict__ Cf, const float* __restrict__ X,
                const float* __restrict__ Dv) {
    __shared__ ushort_t As[128 * 32];
    __shared__ ushort_t Bs[128 * 32];
    const int tid  = threadIdx.x;
    const int lane = tid & 63;
    const int wv   = tid >> 6;
    const int wrow = wv >> 1, wcol = wv & 1;
    const int l15  = lane & 15, lq = lane >> 4;

    const int lin = blockIdx.x;
    const int xcd = lin & 7;
    const int j   = lin >> 3;
    const int mt  = xcd * 32 + (j >> 2);
    const int nt  = j & 3;
    const int m0 = mt * 128;
    const int n0 = nt * 128;

    f32x4 acc[4][4];
#pragma unroll
    for (int i = 0; i < 4; ++i)
#pragma unroll
        for (int jj = 0; jj < 4; ++jj)
            acc[i][jj] = (f32x4){0.f, 0.f, 0.f, 0.f};

    const int grow_l = lane >> 2;
    const int gk8    = (lane & 3) * 8;

    const ushort_t* aF = As + (wrow * 64 + l15) * 32 + lq * 8;
    const ushort_t* bF = Bs + (wcol * 64 + l15) * 32 + lq * 8;

    for (int kt = 0; kt < 1024; kt += 32) {
        __syncthreads();
#pragma unroll
        for (int j2 = 0; j2 < 2; ++j2) {
            const int r0 = j2 * 64 + wv * 16;
            load16_lds(&A[(size_t)(m0 + r0 + grow_l) * 1024 + kt + gk8],
                       (void*)&As[r0 * 32]);
            load16_lds(&Bm[(size_t)(n0 + r0 + grow_l) * 1024 + kt + gk8],
                       (void*)&Bs[r0 * 32]);
        }
        __syncthreads();

        bf16x8 af[4], bfr[4];
#pragma unroll
        for (int mi = 0; mi < 4; ++mi) {
            union { ushort8v u; bf16x8 b; } cv;
            cv.u = *(const ushort8v*)(aF + mi * 512);
            af[mi] = cv.b;
        }
#pragma unroll
        for (int ni = 0; ni < 4; ++ni) {
            union { ushort8v u; bf16x8 b; } cv;
            cv.u = *(const ushort8v*)(bF + ni * 512);
            bfr[ni] = cv.b;
        }
#pragma unroll
        for (int mi = 0; mi < 4; ++mi)
#pragma unroll
            for (int ni = 0; ni < 4; ++ni)
                acc[mi][ni] = __builtin_amdgcn_mfma_f32_16x16x32_bf16(
                    af[mi], bfr[ni], acc[mi][ni], 0, 0, 0);
    }

#pragma unroll
    for (int mi = 0; mi < 4; ++mi)
#pragma unroll
        for (int ni = 0; ni < 4; ++ni) {
            const int col = n0 + wcol * 64 + ni * 16 + l15;
            const float dsum = Dv[col] + Dv[512 + col];
#pragma unroll
            for (int r = 0; r < 4; ++r) {
                const int row = m0 + wrow * 64 + mi * 16 + lq * 4 + r;
                const size_t idx = (size_t)row * 512 + col;
                Cf[idx] = acc[mi][ni][r] + X[idx] * dsum;
            }
        }
}

// ---------------------------------------------------------------------------
// ws layout (bytes):
//  SB   : 0           (67,108,864)  [M][1024] bf16 states both dirs
//  Bm16 : 67,108,864  (1,048,576)
//  Cm16 : 68,157,440  (1,048,576)
//  abar : 69,206,016  (4,096)
//  apow : 69,210,112  (4,096)
//  a32  : 69,214,208  (4,096)
//  pw   : 69,218,304  (524,288)
//  carry: 69,742,592  (1,048,576)
//  init : 70,791,168  (1,048,576)   -> end 71,839,744 (68.5 MB)
extern "C" void kernel_launch(void* const* d_in, const int* in_sizes, int n_in,
                              void* d_out, int out_size, void* d_ws, size_t ws_size,
                              hipStream_t stream) {
    const float* x   = (const float*)d_in[0];
    const float* Lre = (const float*)d_in[1];
    const float* Lim = (const float*)d_in[2];
    const float* ldt = (const float*)d_in[3];
    const float* Bre = (const float*)d_in[4];
    const float* Bim = (const float*)d_in[5];
    const float* Cre = (const float*)d_in[6];
    const float* Cim = (const float*)d_in[7];
    const float* Dv  = (const float*)d_in[8];
    float* y = (float*)d_out;
    char* ws = (char*)d_ws;

    ushort_t* SB   = (ushort_t*)(ws);
    ushort_t* Bm16 = (ushort_t*)(ws + 67108864);
    ushort_t* Cm16 = (ushort_t*)(ws + 68157440);
    float* abar  = (float*)(ws + 69206016);
    float* apow  = (float*)(ws + 69210112);
    float* a32t  = (float*)(ws + 69214208);
    float* pw    = (float*)(ws + 69218304);
    float* carry = (float*)(ws + 69742592);
    float* initb = (float*)(ws + 70791168);

    prep_kernel<<<1024, 256, 0, stream>>>(Lre, Lim, ldt, Bre, Bim, Cre, Cim,
                                          abar, apow, a32t, Bm16, Cm16);
    pw_kernel<<<128, 512, 0, stream>>>(Lre, Lim, ldt, pw);

    gemm1_scan<<<2048, 256, 0, stream>>>(x, Bm16, SB, abar, a32t, carry);
    scan_comb<<<B_SZ, 512, 0, stream>>>(carry, initb, apow);
    correct_kernel<<<16384, 256, 0, stream>>>(SB, pw, initb);
    gemm2_mfma<<<1024, 256, 0, stream>>>(SB, Cm16, y, x, Dv);
}

// Round 5
// 298.724 us; speedup vs baseline: 1.0566x; 1.0566x over previous
//
#include <hip/hip_runtime.h>
#include <math.h>

typedef unsigned short ushort_t;
typedef __bf16 bf16x8 __attribute__((ext_vector_type(8)));
typedef ushort_t ushort8v __attribute__((ext_vector_type(8)));
typedef float f32x4 __attribute__((ext_vector_type(4)));

#define B_SZ   4
#define SEQ    8192
#define M_ROWS (B_SZ * SEQ)   // 32768
#define CH     32
#define NC     (SEQ / CH)     // 256

__device__ __forceinline__ ushort_t f2bf(float f) {
    unsigned u = __float_as_uint(f);
    u = u + 0x7fffu + ((u >> 16) & 1u);
    return (ushort_t)(u >> 16);
}
__device__ __forceinline__ float bf2f(ushort_t b) {
    return __uint_as_float(((unsigned)b) << 16);
}

__device__ __forceinline__ void load16_lds(const void* g, void* l) {
    __builtin_amdgcn_global_load_lds(
        (const __attribute__((address_space(1))) unsigned int*)g,
        (__attribute__((address_space(3))) unsigned int*)l, 16, 0, 0);
}

// ---------------------------------------------------------------------------
// prep: Bmat[k][h] (k = d*512+2p interleaved), Cmat[h][k], abar, apow=a^CH.
__global__ void prep_kernel(const float* __restrict__ Lre,
                            const float* __restrict__ Lim,
                            const float* __restrict__ ldt,
                            const float* __restrict__ Bre,
                            const float* __restrict__ Bim,
                            const float* __restrict__ Cre,
                            const float* __restrict__ Cim,
                            float* __restrict__ abar,
                            float* __restrict__ apow,
                            ushort_t* __restrict__ Bmat,
                            ushort_t* __restrict__ Cmat) {
    int idx = blockIdx.x * 256 + threadIdx.x;   // 0 .. 262143
    int h = idx & 511;
    int p = (idx >> 9) & 255;
    int d = idx >> 17;
    int ip = d * 256 + p;
    float lr = Lre[ip], li = Lim[ip];
    float dt = expf(ldt[ip]);
    float e   = expf(lr * dt);
    float ang = li * dt;
    float ar = e * cosf(ang), ai = e * sinf(ang);
    float nr = ar - 1.0f, ni = ai;
    float den = lr * lr + li * li;
    float cr = (nr * lr + ni * li) / den;
    float ci = (ni * lr - nr * li) / den;
    float br = Bre[idx], bi = Bim[idx];
    Bmat[(d * 512 + 2 * p) * 512 + h]     = f2bf(cr * br - ci * bi);
    Bmat[(d * 512 + 2 * p + 1) * 512 + h] = f2bf(cr * bi + ci * br);
    if (h == 0) {
        int o = d * 512 + 2 * p;
        abar[o] = ar;  abar[o + 1] = ai;
        float eC = expf(lr * dt * (float)CH);
        float aC = ang * (float)CH;
        apow[o] = eC * cosf(aC);  apow[o + 1] = eC * sinf(aC);
    }
    int p2 = idx & 255;
    int h2 = (idx >> 8) & 511;
    int d2 = idx >> 17;
    Cmat[h2 * 1024 + d2 * 512 + 2 * p2]     = f2bf(Cre[idx]);
    Cmat[h2 * 1024 + d2 * 512 + 2 * p2 + 1] = f2bf(-Cim[idx]);
}

__global__ void conv_x_kernel(const float* __restrict__ x,
                              ushort_t* __restrict__ X16) {
    int i = blockIdx.x * 256 + threadIdx.x;
    float4 v = ((const float4*)x)[i];
    ushort_t o[4] = {f2bf(v.x), f2bf(v.y), f2bf(v.z), f2bf(v.w)};
    *(uint2*)&X16[(size_t)i * 4] = *(const uint2*)o;
}

// ---------------------------------------------------------------------------
// bf16 MFMA GEMM (R3-proven), NT n-tiles of 128, K = KD_.
// XCD-swizzled 1D grid: all NT n-tiles of an m-tile adjacent on one XCD.
// EPI 0: Cb = bf16(acc);  EPI 1: Cf = acc + X*(Dv0+Dv1)
template<int EPI, int KD_, int NT>
__global__ __launch_bounds__(256)
void gemm_mfma(const ushort_t* __restrict__ A, const ushort_t* __restrict__ Bm,
               ushort_t* __restrict__ Cb, float* __restrict__ Cf,
               const float* __restrict__ X, const float* __restrict__ Dv) {
    __shared__ ushort_t As[128 * 32];
    __shared__ ushort_t Bs[128 * 32];
    const int tid  = threadIdx.x;
    const int lane = tid & 63;
    const int wv   = tid >> 6;
    const int wrow = wv >> 1, wcol = wv & 1;
    const int l15  = lane & 15, lq = lane >> 4;

    const int lin = blockIdx.x;
    const int xcd = lin & 7;
    const int j   = lin >> 3;
    const int mt  = xcd * 32 + j / NT;
    const int nt  = j % NT;
    const int m0 = mt * 128;
    const int n0 = nt * 128;
    const int CN = NT * 128;

    f32x4 acc[4][4];
#pragma unroll
    for (int i = 0; i < 4; ++i)
#pragma unroll
        for (int jj = 0; jj < 4; ++jj)
            acc[i][jj] = (f32x4){0.f, 0.f, 0.f, 0.f};

    const int grow_l = lane >> 2;
    const int gk8    = (lane & 3) * 8;

    const ushort_t* aF = As + (wrow * 64 + l15) * 32 + lq * 8;
    const ushort_t* bF = Bs + (wcol * 64 + l15) * 32 + lq * 8;

    for (int kt = 0; kt < KD_; kt += 32) {
        __syncthreads();
#pragma unroll
        for (int j2 = 0; j2 < 2; ++j2) {
            const int r0 = j2 * 64 + wv * 16;
            load16_lds(&A[(size_t)(m0 + r0 + grow_l) * KD_ + kt + gk8],
                       (void*)&As[r0 * 32]);
            load16_lds(&Bm[(size_t)(n0 + r0 + grow_l) * KD_ + kt + gk8],
                       (void*)&Bs[r0 * 32]);
        }
        __syncthreads();

        bf16x8 af[4], bfr[4];
#pragma unroll
        for (int mi = 0; mi < 4; ++mi) {
            union { ushort8v u; bf16x8 b; } cv;
            cv.u = *(const ushort8v*)(aF + mi * 512);
            af[mi] = cv.b;
        }
#pragma unroll
        for (int ni = 0; ni < 4; ++ni) {
            union { ushort8v u; bf16x8 b; } cv;
            cv.u = *(const ushort8v*)(bF + ni * 512);
            bfr[ni] = cv.b;
        }
#pragma unroll
        for (int mi = 0; mi < 4; ++mi)
#pragma unroll
            for (int ni = 0; ni < 4; ++ni)
                acc[mi][ni] = __builtin_amdgcn_mfma_f32_16x16x32_bf16(
                    af[mi], bfr[ni], acc[mi][ni], 0, 0, 0);
    }

#pragma unroll
    for (int mi = 0; mi < 4; ++mi) {
#pragma unroll
        for (int ni = 0; ni < 4; ++ni) {
            const int col = n0 + wcol * 64 + ni * 16 + l15;
            float dsum = 0.f;
            if (EPI == 1) dsum = Dv[col] + Dv[512 + col];
#pragma unroll
            for (int r = 0; r < 4; ++r) {
                const int row = m0 + wrow * 64 + mi * 16 + lq * 4 + r;
                if (EPI == 0) {
                    Cb[(size_t)row * CN + col] = f2bf(acc[mi][ni][r]);
                } else {
                    const size_t idx = (size_t)row * 512 + col;
                    Cf[idx] = acc[mi][ni][r] + X[idx] * dsum;
                }
            }
        }
    }
}

// ---------------------------------------------------------------------------
// Scans over SB[row][1024], k = dir*512 + 2p(+1). threads 0..255 dir0 fwd,
// 256..511 dir1 bwd. CH=32, batched 8-wide load/store pipelining.
__global__ __launch_bounds__(512)
void scan_carry(const ushort_t* __restrict__ S, const float* __restrict__ abar,
                float* __restrict__ carry) {
    int b = blockIdx.x, c = blockIdx.y, t = threadIdx.x;
    int dir = t >> 8, p = t & 255;
    float ar = abar[dir * 512 + 2 * p], ai = abar[dir * 512 + 2 * p + 1];
    float sr = 0.f, si = 0.f;
    const ushort_t* base = S + ((size_t)b * SEQ + (size_t)c * CH) * 1024
                             + dir * 512 + 2 * p;
    for (int batch = 0; batch < CH; batch += 8) {
        unsigned v[8];
#pragma unroll
        for (int q = 0; q < 8; ++q) {
            int l = batch + q;
            int row = dir ? (CH - 1 - l) : l;
            v[q] = *(const unsigned*)(base + (size_t)row * 1024);
        }
#pragma unroll
        for (int q = 0; q < 8; ++q) {
            float re = bf2f((ushort_t)(v[q] & 0xffffu));
            float im = bf2f((ushort_t)(v[q] >> 16));
            float nr = fmaf(ar, sr, fmaf(-ai, si, re));
            float ni = fmaf(ar, si, fmaf(ai, sr, im));
            sr = nr; si = ni;
        }
    }
    int o = (b * NC + c) * 1024 + dir * 512 + 2 * p;
    carry[o] = sr; carry[o + 1] = si;
}

__global__ __launch_bounds__(512)
void scan_comb(const float* __restrict__ carry, float* __restrict__ init,
               const float* __restrict__ apow) {
    int b = blockIdx.x, t = threadIdx.x;
    int dir = t >> 8, p = t & 255;
    float pr = apow[dir * 512 + 2 * p], pi = apow[dir * 512 + 2 * p + 1];
    float sr = 0.f, si = 0.f;
#pragma unroll 8
    for (int cc = 0; cc < NC; ++cc) {
        int c = dir ? (NC - 1 - cc) : cc;
        int o = (b * NC + c) * 1024 + dir * 512 + 2 * p;
        init[o] = sr; init[o + 1] = si;
        float cr = carry[o], ci = carry[o + 1];
        float nr = fmaf(pr, sr, fmaf(-pi, si, cr));
        float ni = fmaf(pr, si, fmaf(pi, sr, ci));
        sr = nr; si = ni;
    }
}

__global__ __launch_bounds__(512)
void scan_final(ushort_t* __restrict__ S, const float* __restrict__ abar,
                const float* __restrict__ init) {
    int b = blockIdx.x, c = blockIdx.y, t = threadIdx.x;
    int dir = t >> 8, p = t & 255;
    float ar = abar[dir * 512 + 2 * p], ai = abar[dir * 512 + 2 * p + 1];
    int o = (b * NC + c) * 1024 + dir * 512 + 2 * p;
    float sr = init[o], si = init[o + 1];
    ushort_t* base = S + ((size_t)b * SEQ + (size_t)c * CH) * 1024
                       + dir * 512 + 2 * p;
    for (int batch = 0; batch < CH; batch += 8) {
        unsigned v[8];
#pragma unroll
        for (int q = 0; q < 8; ++q) {
            int l = batch + q;
            int row = dir ? (CH - 1 - l) : l;
            v[q] = *(const unsigned*)(base + (size_t)row * 1024);
        }
#pragma unroll
        for (int q = 0; q < 8; ++q) {
            float re = bf2f((ushort_t)(v[q] & 0xffffu));
            float im = bf2f((ushort_t)(v[q] >> 16));
            float nr = fmaf(ar, sr, fmaf(-ai, si, re));
            float ni = fmaf(ar, si, fmaf(ai, sr, im));
            sr = nr; si = ni;
            v[q] = ((unsigned)f2bf(si) << 16) | (unsigned)f2bf(sr);
        }
#pragma unroll
        for (int q = 0; q < 8; ++q) {
            int l = batch + q;
            int row = dir ? (CH - 1 - l) : l;
            *(unsigned*)(base + (size_t)row * 1024) = v[q];
        }
    }
}

// ---------------------------------------------------------------------------
// ws layout (bytes):
//  SB   : 0           (67,108,864)  [M][1024] bf16 states both dirs
//  Bm16 : 67,108,864  (1,048,576)
//  Cm16 : 68,157,440  (1,048,576)
//  abar : 69,206,016  (4,096)
//  apow : 69,210,112  (4,096)
//  X16  : 69,214,208  (33,554,432) -> end 102,768,640
//  carry: 69,214,208  (4,194,304)   alias over X16 (dead after GEMM1)
//  init : 73,408,512  (4,194,304)   alias
extern "C" void kernel_launch(void* const* d_in, const int* in_sizes, int n_in,
                              void* d_out, int out_size, void* d_ws, size_t ws_size,
                              hipStream_t stream) {
    const float* x   = (const float*)d_in[0];
    const float* Lre = (const float*)d_in[1];
    const float* Lim = (const float*)d_in[2];
    const float* ldt = (const float*)d_in[3];
    const float* Bre = (const float*)d_in[4];
    const float* Bim = (const float*)d_in[5];
    const float* Cre = (const float*)d_in[6];
    const float* Cim = (const float*)d_in[7];
    const float* Dv  = (const float*)d_in[8];
    float* y = (float*)d_out;
    char* ws = (char*)d_ws;

    ushort_t* SB   = (ushort_t*)(ws);
    ushort_t* Bm16 = (ushort_t*)(ws + 67108864);
    ushort_t* Cm16 = (ushort_t*)(ws + 68157440);
    float* abar  = (float*)(ws + 69206016);
    float* apow  = (float*)(ws + 69210112);
    ushort_t* X16  = (ushort_t*)(ws + 69214208);
    float* carry = (float*)(ws + 69214208);   // alias (X16 dead after GEMM1)
    float* initb = (float*)(ws + 73408512);

    prep_kernel<<<1024, 256, 0, stream>>>(Lre, Lim, ldt, Bre, Bim, Cre, Cim,
                                          abar, apow, Bm16, Cm16);
    conv_x_kernel<<<16384, 256, 0, stream>>>(x, X16);

    // GEMM1: SB[M][1024] = X16[M][512] * Bm16[1024][512]^T
    gemm_mfma<0, 512, 8><<<2048, 256, 0, stream>>>(X16, Bm16, SB, nullptr,
                                                   nullptr, nullptr);

    dim3 gs(B_SZ, NC);
    scan_carry<<<gs, 512, 0, stream>>>(SB, abar, carry);
    scan_comb<<<B_SZ, 512, 0, stream>>>(carry, initb, apow);
    scan_final<<<gs, 512, 0, stream>>>(SB, abar, initb);

    // GEMM2: y[M][512] = SB[M][1024] * Cm16[512][1024]^T + x*(D0+D1)
    gemm_mfma<1, 1024, 4><<<1024, 256, 0, stream>>>(SB, Cm16, nullptr, y,
                                                    x, Dv);
}